// Round 1
// baseline (4217.588 us; speedup 1.0000x reference)
//
#include <hip/hip_runtime.h>

#define N_NODES 50000
#define N_EDGES 800000
#define D 128
#define L 3

// ---------------- degree / normalization ----------------

__global__ __launch_bounds__(256) void deg_init_k(unsigned int* deg) {
  int i = blockIdx.x * 256 + threadIdx.x;
  if (i < N_NODES) deg[i] = 1u;  // self-loop
}

__global__ __launch_bounds__(256) void deg_count_k(const int* __restrict__ col,
                                                   unsigned int* deg) {
  int e = blockIdx.x * 256 + threadIdx.x;
  if (e < N_EDGES) atomicAdd(&deg[col[e]], 1u);
}

__global__ __launch_bounds__(256) void dinv_k(float* dinv_f, const unsigned int* deg) {
  int i = blockIdx.x * 256 + threadIdx.x;
  if (i < N_NODES) {
    unsigned int d = deg[i];
    dinv_f[i] = rsqrtf((float)d);
  }
}

// ---------------- aggregation: AGG = A_norm * Z ----------------

// self-loop term: AGG[i] = Z[i] * dinv[i]^2   (one float4 per thread)
__global__ __launch_bounds__(256) void agg_init_k(const float* __restrict__ Z,
                                                  const float* __restrict__ dinv,
                                                  float* __restrict__ AGG) {
  int t = blockIdx.x * 256 + threadIdx.x;  // N*32 float4s
  if (t >= N_NODES * 32) return;
  int i = t >> 5;
  float s = dinv[i];
  s *= s;
  float4 v = ((const float4*)Z)[t];
  v.x *= s; v.y *= s; v.z *= s; v.w *= s;
  ((float4*)AGG)[t] = v;
}

// edges: AGG[col] += Z[row] * dinv[row]*dinv[col]; 32 threads per edge (float4 each)
__global__ __launch_bounds__(256) void scatter_k(const int* __restrict__ rows,
                                                 const int* __restrict__ cols,
                                                 const float* __restrict__ dinv,
                                                 const float* __restrict__ Z,
                                                 float* __restrict__ AGG) {
  int t = blockIdx.x * 256 + threadIdx.x;
  int e = t >> 5;
  if (e >= N_EDGES) return;
  int c = t & 31;
  int r = rows[e], cl = cols[e];
  float nrm = dinv[r] * dinv[cl];
  float4 v = ((const float4*)(Z + (size_t)r * D))[c];
  float* dst = AGG + (size_t)cl * D + c * 4;
  unsafeAtomicAdd(dst + 0, v.x * nrm);
  unsafeAtomicAdd(dst + 1, v.y * nrm);
  unsafeAtomicAdd(dst + 2, v.z * nrm);
  unsafeAtomicAdd(dst + 3, v.w * nrm);
}

// ---------------- fused GEMM + bias + PReLU ----------------
// out[r][c] = prelu( sum_k P[r][k] * W[k][c] + b[c], alpha[c] )
// 64 rows per block, 256 threads, each thread 4 rows x 8 cols micro-tile.
// K staged in 2 chunks of 64 (LDS: 32KB W + 16KB Z^T = 48KB <= 64KB).
__global__ __launch_bounds__(256) void gemm_k(const float* __restrict__ P,
                                              const float* __restrict__ W,
                                              const float* __restrict__ bias,
                                              const float* __restrict__ alpha,
                                              float* __restrict__ out) {
  __shared__ float sW[64 * 128];  // [k_local][c]
  __shared__ float sZ[64 * 64];   // [k_local][r]  (transposed tile)
  const int tid = threadIdx.x;
  const int r_base = blockIdx.x * 64;
  const int cg = tid & 15, rg = tid >> 4;
  const int c0 = cg * 8, r0 = rg * 4;
  float acc[4][8];
#pragma unroll
  for (int i = 0; i < 4; ++i)
#pragma unroll
    for (int j = 0; j < 8; ++j) acc[i][j] = 0.f;

  for (int kc = 0; kc < 128; kc += 64) {
    // stage W[kc..kc+63][0..127]  (2048 float4 / 256 thr = 8 each, coalesced)
    for (int i = tid; i < 64 * 128 / 4; i += 256)
      ((float4*)sW)[i] = ((const float4*)(W + (size_t)kc * 128))[i];
    // stage Z^T: sZ[k][r] from P[r_base+r][kc+k]
    for (int i = tid; i < 64 * 16; i += 256) {
      int r = i >> 4, k4 = i & 15;
      int gr = r_base + r;
      float4 v = make_float4(0.f, 0.f, 0.f, 0.f);
      if (gr < N_NODES) v = ((const float4*)(P + (size_t)gr * D + kc))[k4];
      sZ[(k4 * 4 + 0) * 64 + r] = v.x;
      sZ[(k4 * 4 + 1) * 64 + r] = v.y;
      sZ[(k4 * 4 + 2) * 64 + r] = v.z;
      sZ[(k4 * 4 + 3) * 64 + r] = v.w;
    }
    __syncthreads();
#pragma unroll 4
    for (int k = 0; k < 64; ++k) {
      float4 z4 = *(const float4*)&sZ[k * 64 + r0];
      float4 wa = *(const float4*)&sW[k * 128 + c0];
      float4 wb = *(const float4*)&sW[k * 128 + c0 + 4];
      float zz[4] = {z4.x, z4.y, z4.z, z4.w};
      float ww[8] = {wa.x, wa.y, wa.z, wa.w, wb.x, wb.y, wb.z, wb.w};
#pragma unroll
      for (int i = 0; i < 4; ++i)
#pragma unroll
        for (int j = 0; j < 8; ++j) acc[i][j] = fmaf(zz[i], ww[j], acc[i][j]);
    }
    __syncthreads();
  }

  float bl[8], al[8];
#pragma unroll
  for (int j = 0; j < 8; ++j) {
    bl[j] = bias[c0 + j];
    al[j] = alpha[c0 + j];
  }
#pragma unroll
  for (int i = 0; i < 4; ++i) {
    int gr = r_base + r0 + i;
    if (gr >= N_NODES) continue;
    float o[8];
#pragma unroll
    for (int j = 0; j < 8; ++j) {
      float v = acc[i][j] + bl[j];
      o[j] = v >= 0.f ? v : al[j] * v;
    }
    float4* dst = (float4*)(out + (size_t)gr * D + c0);
    dst[0] = make_float4(o[0], o[1], o[2], o[3]);
    dst[1] = make_float4(o[4], o[5], o[6], o[7]);
  }
}

// ---------------- launch ----------------

extern "C" void kernel_launch(void* const* d_in, const int* in_sizes, int n_in,
                              void* d_out, int out_size, void* d_ws, size_t ws_size,
                              hipStream_t stream) {
  const float* x      = (const float*)d_in[0];
  const int*   ei     = (const int*)d_in[1];   // [2, E] int32
  const float* Ws     = (const float*)d_in[2]; // [L, D, D]
  const float* bs     = (const float*)d_in[3]; // [L, D]
  const float* alphas = (const float*)d_in[4]; // [L, D]
  float* out = (float*)d_out;

  const int* rows = ei;             // edge_index[0] : source
  const int* cols = ei + N_EDGES;   // edge_index[1] : target

  char* ws = (char*)d_ws;
  float*        dinv = (float*)ws;           // N floats (deg counted in-place as uint)
  unsigned int* deg  = (unsigned int*)ws;
  float* AGG = (float*)(ws + (((size_t)N_NODES * 4 + 255) / 256) * 256);
  float* Z = out;  // layer output buffer == d_out (rewritten every layer)

  deg_init_k<<<(N_NODES + 255) / 256, 256, 0, stream>>>(deg);
  deg_count_k<<<(N_EDGES + 255) / 256, 256, 0, stream>>>(cols, deg);
  dinv_k<<<(N_NODES + 255) / 256, 256, 0, stream>>>(dinv, deg);

  for (int l = 0; l < L; ++l) {
    const float* zin = (l == 0) ? x : Z;
    agg_init_k<<<(N_NODES * 32 + 255) / 256, 256, 0, stream>>>(zin, dinv, AGG);
    scatter_k<<<((size_t)N_EDGES * 32 + 255) / 256, 256, 0, stream>>>(rows, cols, dinv, zin, AGG);
    gemm_k<<<(N_NODES + 63) / 64, 256, 0, stream>>>(
        AGG, Ws + (size_t)l * D * D, bs + (size_t)l * D, alphas + (size_t)l * D, Z);
  }
}

// Round 2
// 502.042 us; speedup vs baseline: 8.4009x; 8.4009x over previous
//
#include <hip/hip_runtime.h>

#define N_NODES 50000
#define N_EDGES 800000
#define D 128
#define L 3

// ---------------- degree / normalization ----------------

__global__ __launch_bounds__(256) void deg_init_k(unsigned int* deg) {
  int i = blockIdx.x * 256 + threadIdx.x;
  if (i < N_NODES) deg[i] = 1u;  // self-loop
}

__global__ __launch_bounds__(256) void deg_count_k(const int* __restrict__ col,
                                                   unsigned int* deg) {
  int e = blockIdx.x * 256 + threadIdx.x;
  if (e < N_EDGES) atomicAdd(&deg[col[e]], 1u);
}

__global__ __launch_bounds__(256) void dinv_k(float* dinv_f, const unsigned int* deg) {
  int i = blockIdx.x * 256 + threadIdx.x;
  if (i < N_NODES) dinv_f[i] = rsqrtf((float)deg[i]);
}

// ---------------- CSR build ----------------
// exclusive scan of (deg[i]-1) -> rowptr[0..N], and fill[i]=rowptr[i].
// fill aliases deg (read-before-write per index by same thread).
__global__ __launch_bounds__(1024) void scan_k(unsigned int* deg_fill,
                                               unsigned int* rowptr) {
  __shared__ unsigned int buf[1024];
  __shared__ unsigned int carry;
  const int tid = threadIdx.x;
  if (tid == 0) carry = 0u;
  __syncthreads();
  for (int base = 0; base < N_NODES; base += 1024) {
    int i = base + tid;
    unsigned int d = (i < N_NODES) ? (deg_fill[i] - 1u) : 0u;  // edges only
    buf[tid] = d;
    __syncthreads();
    for (int off = 1; off < 1024; off <<= 1) {
      unsigned int t = (tid >= off) ? buf[tid - off] : 0u;
      __syncthreads();
      buf[tid] += t;
      __syncthreads();
    }
    unsigned int inc = buf[tid];
    unsigned int c0 = carry;
    unsigned int excl = c0 + inc - d;
    if (i < N_NODES) {
      rowptr[i] = excl;
      deg_fill[i] = excl;  // fill cursor
    }
    __syncthreads();
    if (tid == 1023) carry = c0 + buf[1023];
    __syncthreads();
  }
  if (tid == 0) rowptr[N_NODES] = carry;
}

__global__ __launch_bounds__(256) void fill_k(const int* __restrict__ rows,
                                              const int* __restrict__ cols,
                                              unsigned int* fill,
                                              unsigned int* __restrict__ csr) {
  int e = blockIdx.x * 256 + threadIdx.x;
  if (e >= N_EDGES) return;
  unsigned int pos = atomicAdd(&fill[cols[e]], 1u);
  csr[pos] = (unsigned int)rows[e];
}

// ---------------- aggregation: AGG = A_norm * Z  (gather, no atomics) ----------
// one wave (64 lanes) per target node; lane holds float2 (D=128).
__global__ __launch_bounds__(256) void gather_k(const unsigned int* __restrict__ rowptr,
                                                const unsigned int* __restrict__ csr,
                                                const float* __restrict__ dinv,
                                                const float* __restrict__ Z,
                                                float* __restrict__ AGG) {
  int wid = (blockIdx.x * 256 + threadIdx.x) >> 6;  // node id
  int lane = threadIdx.x & 63;
  if (wid >= N_NODES) return;
  const float2* Z2 = (const float2*)Z;
  float di = dinv[wid];
  float2 z = Z2[(size_t)wid * 64 + lane];
  float2 sum;
  sum.x = di * z.x;
  sum.y = di * z.y;
  unsigned int p = rowptr[wid], p1 = rowptr[wid + 1];
  for (; p + 2 <= p1; p += 2) {
    unsigned int s0 = csr[p], s1 = csr[p + 1];
    float w0 = dinv[s0], w1 = dinv[s1];
    float2 v0 = Z2[(size_t)s0 * 64 + lane];
    float2 v1 = Z2[(size_t)s1 * 64 + lane];
    sum.x += w0 * v0.x + w1 * v1.x;
    sum.y += w0 * v0.y + w1 * v1.y;
  }
  if (p < p1) {
    unsigned int s0 = csr[p];
    float w0 = dinv[s0];
    float2 v0 = Z2[(size_t)s0 * 64 + lane];
    sum.x += w0 * v0.x;
    sum.y += w0 * v0.y;
  }
  sum.x *= di;
  sum.y *= di;
  ((float2*)AGG)[(size_t)wid * 64 + lane] = sum;
}

// ---------------- fused GEMM + bias + PReLU ----------------
__global__ __launch_bounds__(256) void gemm_k(const float* __restrict__ P,
                                              const float* __restrict__ W,
                                              const float* __restrict__ bias,
                                              const float* __restrict__ alpha,
                                              float* __restrict__ out) {
  __shared__ float sW[64 * 128];  // [k_local][c]
  __shared__ float sZ[64 * 64];   // [k_local][r]
  const int tid = threadIdx.x;
  const int r_base = blockIdx.x * 64;
  const int cg = tid & 15, rg = tid >> 4;
  const int c0 = cg * 8, r0 = rg * 4;
  float acc[4][8];
#pragma unroll
  for (int i = 0; i < 4; ++i)
#pragma unroll
    for (int j = 0; j < 8; ++j) acc[i][j] = 0.f;

  for (int kc = 0; kc < 128; kc += 64) {
    for (int i = tid; i < 64 * 128 / 4; i += 256)
      ((float4*)sW)[i] = ((const float4*)(W + (size_t)kc * 128))[i];
    for (int i = tid; i < 64 * 16; i += 256) {
      int r = i >> 4, k4 = i & 15;
      int gr = r_base + r;
      float4 v = make_float4(0.f, 0.f, 0.f, 0.f);
      if (gr < N_NODES) v = ((const float4*)(P + (size_t)gr * D + kc))[k4];
      sZ[(k4 * 4 + 0) * 64 + r] = v.x;
      sZ[(k4 * 4 + 1) * 64 + r] = v.y;
      sZ[(k4 * 4 + 2) * 64 + r] = v.z;
      sZ[(k4 * 4 + 3) * 64 + r] = v.w;
    }
    __syncthreads();
#pragma unroll 4
    for (int k = 0; k < 64; ++k) {
      float4 z4 = *(const float4*)&sZ[k * 64 + r0];
      float4 wa = *(const float4*)&sW[k * 128 + c0];
      float4 wb = *(const float4*)&sW[k * 128 + c0 + 4];
      float zz[4] = {z4.x, z4.y, z4.z, z4.w};
      float ww[8] = {wa.x, wa.y, wa.z, wa.w, wb.x, wb.y, wb.z, wb.w};
#pragma unroll
      for (int i = 0; i < 4; ++i)
#pragma unroll
        for (int j = 0; j < 8; ++j) acc[i][j] = fmaf(zz[i], ww[j], acc[i][j]);
    }
    __syncthreads();
  }

  float bl[8], al[8];
#pragma unroll
  for (int j = 0; j < 8; ++j) {
    bl[j] = bias[c0 + j];
    al[j] = alpha[c0 + j];
  }
#pragma unroll
  for (int i = 0; i < 4; ++i) {
    int gr = r_base + r0 + i;
    if (gr >= N_NODES) continue;
    float o[8];
#pragma unroll
    for (int j = 0; j < 8; ++j) {
      float v = acc[i][j] + bl[j];
      o[j] = v >= 0.f ? v : al[j] * v;
    }
    float4* dst = (float4*)(out + (size_t)gr * D + c0);
    dst[0] = make_float4(o[0], o[1], o[2], o[3]);
    dst[1] = make_float4(o[4], o[5], o[6], o[7]);
  }
}

// ---------------- launch ----------------

extern "C" void kernel_launch(void* const* d_in, const int* in_sizes, int n_in,
                              void* d_out, int out_size, void* d_ws, size_t ws_size,
                              hipStream_t stream) {
  const float* x      = (const float*)d_in[0];
  const int*   ei     = (const int*)d_in[1];   // [2, E] int32
  const float* Ws     = (const float*)d_in[2];
  const float* bs     = (const float*)d_in[3];
  const float* alphas = (const float*)d_in[4];
  float* out = (float*)d_out;

  const int* rows = ei;            // source
  const int* cols = ei + N_EDGES;  // target

  char* ws = (char*)d_ws;
  const size_t NPAD = (((size_t)N_NODES * 4 + 255) / 256) * 256;       // 200192
  const size_t NP1PAD = ((((size_t)N_NODES + 1) * 4 + 255) / 256) * 256;
  float*        dinv   = (float*)ws;                       ws += NPAD;
  unsigned int* rowptr = (unsigned int*)ws;                ws += NP1PAD;
  unsigned int* degfill= (unsigned int*)ws;                ws += NPAD;
  unsigned int* csr    = (unsigned int*)ws;                ws += (size_t)N_EDGES * 4;
  float*        AGG    = (float*)ws;
  float* Z = out;

  deg_init_k<<<(N_NODES + 255) / 256, 256, 0, stream>>>(degfill);
  deg_count_k<<<(N_EDGES + 255) / 256, 256, 0, stream>>>(cols, degfill);
  dinv_k<<<(N_NODES + 255) / 256, 256, 0, stream>>>(dinv, degfill);
  scan_k<<<1, 1024, 0, stream>>>(degfill, rowptr);
  fill_k<<<(N_EDGES + 255) / 256, 256, 0, stream>>>(rows, cols, degfill, csr);

  for (int l = 0; l < L; ++l) {
    const float* zin = (l == 0) ? x : Z;
    gather_k<<<(N_NODES * 64 + 255) / 256, 256, 0, stream>>>(rowptr, csr, dinv, zin, AGG);
    gemm_k<<<(N_NODES + 63) / 64, 256, 0, stream>>>(
        AGG, Ws + (size_t)l * D * D, bs + (size_t)l * D, alphas + (size_t)l * D, Z);
  }
}

// Round 3
// 417.335 us; speedup vs baseline: 10.1060x; 1.2030x over previous
//
#include <hip/hip_runtime.h>

#define N_NODES 50000
#define N_EDGES 800000
#define D 128
#define L 3
#define SCAN_B 1024
#define SCAN_NB ((N_NODES + SCAN_B - 1) / SCAN_B)  // 49

// ---------------- degree / normalization ----------------

__global__ __launch_bounds__(256) void deg_init_k(unsigned int* deg) {
  int i = blockIdx.x * 256 + threadIdx.x;
  if (i < N_NODES) deg[i] = 1u;  // self-loop
}

__global__ __launch_bounds__(256) void deg_count_k(const int* __restrict__ col,
                                                   unsigned int* deg) {
  int e = blockIdx.x * 256 + threadIdx.x;
  if (e < N_EDGES) atomicAdd(&deg[col[e]], 1u);
}

__global__ __launch_bounds__(256) void dinv_k(float* dinv_f, const unsigned int* deg) {
  int i = blockIdx.x * 256 + threadIdx.x;
  if (i < N_NODES) dinv_f[i] = rsqrtf((float)deg[i]);
}

// ---------------- CSR build: hierarchical scan ----------------
// scan1: per-block exclusive scan of (deg-1); local result -> rowptr, block sum -> bsum
__global__ __launch_bounds__(SCAN_B) void scan1_k(const unsigned int* __restrict__ deg,
                                                  unsigned int* __restrict__ rowptr,
                                                  unsigned int* __restrict__ bsum) {
  __shared__ unsigned int buf[SCAN_B];
  const int tid = threadIdx.x;
  const int i = blockIdx.x * SCAN_B + tid;
  unsigned int d = (i < N_NODES) ? (deg[i] - 1u) : 0u;
  buf[tid] = d;
  __syncthreads();
  for (int off = 1; off < SCAN_B; off <<= 1) {
    unsigned int t = (tid >= off) ? buf[tid - off] : 0u;
    __syncthreads();
    buf[tid] += t;
    __syncthreads();
  }
  if (i < N_NODES) rowptr[i] = buf[tid] - d;  // local exclusive
  if (tid == SCAN_B - 1) bsum[blockIdx.x] = buf[tid];
}

// scan2: one wave scans the block sums -> exclusive offsets + total
__global__ __launch_bounds__(64) void scan2_k(const unsigned int* __restrict__ bsum,
                                              unsigned int* __restrict__ boff,
                                              unsigned int* __restrict__ rowptr) {
  int lane = threadIdx.x;
  unsigned int v = (lane < SCAN_NB) ? bsum[lane] : 0u;
  unsigned int incl = v;
#pragma unroll
  for (int off = 1; off < 64; off <<= 1) {
    unsigned int t = __shfl_up(incl, off, 64);
    if (lane >= off) incl += t;
  }
  if (lane < SCAN_NB) boff[lane] = incl - v;
  if (lane == 63) rowptr[N_NODES] = incl;  // total == N_EDGES
}

// scan3: add block offset; final rowptr + fill cursor
__global__ __launch_bounds__(SCAN_B) void scan3_k(const unsigned int* __restrict__ boff,
                                                  unsigned int* __restrict__ rowptr,
                                                  unsigned int* __restrict__ fill) {
  int i = blockIdx.x * SCAN_B + threadIdx.x;
  if (i < N_NODES) {
    unsigned int r = rowptr[i] + boff[blockIdx.x];
    rowptr[i] = r;
    fill[i] = r;
  }
}

__global__ __launch_bounds__(256) void fill_k(const int* __restrict__ rows,
                                              const int* __restrict__ cols,
                                              unsigned int* fill,
                                              unsigned int* __restrict__ csr) {
  int e = blockIdx.x * 256 + threadIdx.x;
  if (e >= N_EDGES) return;
  unsigned int pos = atomicAdd(&fill[cols[e]], 1u);
  csr[pos] = (unsigned int)rows[e];
}

// ---------------- aggregation: AGG = A_norm * Z  (gather, no atomics) ----------
__global__ __launch_bounds__(256) void gather_k(const unsigned int* __restrict__ rowptr,
                                                const unsigned int* __restrict__ csr,
                                                const float* __restrict__ dinv,
                                                const float* __restrict__ Z,
                                                float* __restrict__ AGG) {
  int wid = (blockIdx.x * 256 + threadIdx.x) >> 6;  // node id
  int lane = threadIdx.x & 63;
  if (wid >= N_NODES) return;
  const float2* Z2 = (const float2*)Z;
  float di = dinv[wid];
  float2 z = Z2[(size_t)wid * 64 + lane];
  float2 sum;
  sum.x = di * z.x;
  sum.y = di * z.y;
  unsigned int p = rowptr[wid], p1 = rowptr[wid + 1];
  for (; p + 2 <= p1; p += 2) {
    unsigned int s0 = csr[p], s1 = csr[p + 1];
    float w0 = dinv[s0], w1 = dinv[s1];
    float2 v0 = Z2[(size_t)s0 * 64 + lane];
    float2 v1 = Z2[(size_t)s1 * 64 + lane];
    sum.x += w0 * v0.x + w1 * v1.x;
    sum.y += w0 * v0.y + w1 * v1.y;
  }
  if (p < p1) {
    unsigned int s0 = csr[p];
    float w0 = dinv[s0];
    float2 v0 = Z2[(size_t)s0 * 64 + lane];
    sum.x += w0 * v0.x;
    sum.y += w0 * v0.y;
  }
  sum.x *= di;
  sum.y *= di;
  ((float2*)AGG)[(size_t)wid * 64 + lane] = sum;
}

// ---------------- fused GEMM + bias + PReLU ----------------
__global__ __launch_bounds__(256) void gemm_k(const float* __restrict__ P,
                                              const float* __restrict__ W,
                                              const float* __restrict__ bias,
                                              const float* __restrict__ alpha,
                                              float* __restrict__ out) {
  __shared__ float sW[64 * 128];  // [k_local][c]
  __shared__ float sZ[64 * 64];   // [k_local][r]
  const int tid = threadIdx.x;
  const int r_base = blockIdx.x * 64;
  const int cg = tid & 15, rg = tid >> 4;
  const int c0 = cg * 8, r0 = rg * 4;
  float acc[4][8];
#pragma unroll
  for (int i = 0; i < 4; ++i)
#pragma unroll
    for (int j = 0; j < 8; ++j) acc[i][j] = 0.f;

  for (int kc = 0; kc < 128; kc += 64) {
    for (int i = tid; i < 64 * 128 / 4; i += 256)
      ((float4*)sW)[i] = ((const float4*)(W + (size_t)kc * 128))[i];
    for (int i = tid; i < 64 * 16; i += 256) {
      int r = i >> 4, k4 = i & 15;
      int gr = r_base + r;
      float4 v = make_float4(0.f, 0.f, 0.f, 0.f);
      if (gr < N_NODES) v = ((const float4*)(P + (size_t)gr * D + kc))[k4];
      sZ[(k4 * 4 + 0) * 64 + r] = v.x;
      sZ[(k4 * 4 + 1) * 64 + r] = v.y;
      sZ[(k4 * 4 + 2) * 64 + r] = v.z;
      sZ[(k4 * 4 + 3) * 64 + r] = v.w;
    }
    __syncthreads();
#pragma unroll 4
    for (int k = 0; k < 64; ++k) {
      float4 z4 = *(const float4*)&sZ[k * 64 + r0];
      float4 wa = *(const float4*)&sW[k * 128 + c0];
      float4 wb = *(const float4*)&sW[k * 128 + c0 + 4];
      float zz[4] = {z4.x, z4.y, z4.z, z4.w};
      float ww[8] = {wa.x, wa.y, wa.z, wa.w, wb.x, wb.y, wb.z, wb.w};
#pragma unroll
      for (int i = 0; i < 4; ++i)
#pragma unroll
        for (int j = 0; j < 8; ++j) acc[i][j] = fmaf(zz[i], ww[j], acc[i][j]);
    }
    __syncthreads();
  }

  float bl[8], al[8];
#pragma unroll
  for (int j = 0; j < 8; ++j) {
    bl[j] = bias[c0 + j];
    al[j] = alpha[c0 + j];
  }
#pragma unroll
  for (int i = 0; i < 4; ++i) {
    int gr = r_base + r0 + i;
    if (gr >= N_NODES) continue;
    float o[8];
#pragma unroll
    for (int j = 0; j < 8; ++j) {
      float v = acc[i][j] + bl[j];
      o[j] = v >= 0.f ? v : al[j] * v;
    }
    float4* dst = (float4*)(out + (size_t)gr * D + c0);
    dst[0] = make_float4(o[0], o[1], o[2], o[3]);
    dst[1] = make_float4(o[4], o[5], o[6], o[7]);
  }
}

// ---------------- launch ----------------

extern "C" void kernel_launch(void* const* d_in, const int* in_sizes, int n_in,
                              void* d_out, int out_size, void* d_ws, size_t ws_size,
                              hipStream_t stream) {
  const float* x      = (const float*)d_in[0];
  const int*   ei     = (const int*)d_in[1];   // [2, E] int32
  const float* Ws     = (const float*)d_in[2];
  const float* bs     = (const float*)d_in[3];
  const float* alphas = (const float*)d_in[4];
  float* out = (float*)d_out;

  const int* rows = ei;            // source
  const int* cols = ei + N_EDGES;  // target

  char* ws = (char*)d_ws;
  const size_t NPAD = (((size_t)N_NODES * 4 + 255) / 256) * 256;
  const size_t NP1PAD = ((((size_t)N_NODES + 1) * 4 + 255) / 256) * 256;
  float*        dinv   = (float*)ws;             ws += NPAD;
  unsigned int* rowptr = (unsigned int*)ws;      ws += NP1PAD;
  unsigned int* degfill= (unsigned int*)ws;      ws += NPAD;
  unsigned int* bsum   = (unsigned int*)ws;      ws += 256;  // 49 uints
  unsigned int* boff   = (unsigned int*)ws;      ws += 256;
  unsigned int* csr    = (unsigned int*)ws;      ws += (size_t)N_EDGES * 4;
  float*        AGG    = (float*)ws;
  float* Z = out;

  deg_init_k<<<(N_NODES + 255) / 256, 256, 0, stream>>>(degfill);
  deg_count_k<<<(N_EDGES + 255) / 256, 256, 0, stream>>>(cols, degfill);
  dinv_k<<<(N_NODES + 255) / 256, 256, 0, stream>>>(dinv, degfill);
  scan1_k<<<SCAN_NB, SCAN_B, 0, stream>>>(degfill, rowptr, bsum);
  scan2_k<<<1, 64, 0, stream>>>(bsum, boff, rowptr);
  scan3_k<<<SCAN_NB, SCAN_B, 0, stream>>>(boff, rowptr, degfill);
  fill_k<<<(N_EDGES + 255) / 256, 256, 0, stream>>>(rows, cols, degfill, csr);

  for (int l = 0; l < L; ++l) {
    const float* zin = (l == 0) ? x : Z;
    gather_k<<<(N_NODES * 64 + 255) / 256, 256, 0, stream>>>(rowptr, csr, dinv, zin, AGG);
    gemm_k<<<(N_NODES + 63) / 64, 256, 0, stream>>>(
        AGG, Ws + (size_t)l * D * D, bs + (size_t)l * D, alphas + (size_t)l * D, Z);
  }
}

// Round 4
// 342.438 us; speedup vs baseline: 12.3164x; 1.2187x over previous
//
#include <hip/hip_runtime.h>

#define N_NODES 50000
#define N_EDGES 800000
#define D 128
#define L 3
#define SCAN_B 1024
#define SCAN_NB ((N_NODES + SCAN_B - 1) / SCAN_B)  // 49

// ---------------- degree / normalization ----------------

__global__ __launch_bounds__(256) void deg_init_k(unsigned int* deg) {
  int i = blockIdx.x * 256 + threadIdx.x;
  if (i < N_NODES) deg[i] = 1u;  // self-loop
}

// count degree AND capture per-edge rank (old counter value) -> no atomics needed in fill
__global__ __launch_bounds__(256) void deg_count_k(const int* __restrict__ col,
                                                   unsigned int* deg,
                                                   unsigned int* __restrict__ rank) {
  int e = blockIdx.x * 256 + threadIdx.x;
  if (e < N_EDGES) rank[e] = atomicAdd(&deg[col[e]], 1u);  // >=1 (init 1)
}

__global__ __launch_bounds__(256) void dinv_k(float* dinv_f, const unsigned int* deg) {
  int i = blockIdx.x * 256 + threadIdx.x;
  if (i < N_NODES) dinv_f[i] = rsqrtf((float)deg[i]);
}

// ---------------- CSR build: hierarchical scan ----------------
__global__ __launch_bounds__(SCAN_B) void scan1_k(const unsigned int* __restrict__ deg,
                                                  unsigned int* __restrict__ rowptr,
                                                  unsigned int* __restrict__ bsum) {
  __shared__ unsigned int buf[SCAN_B];
  const int tid = threadIdx.x;
  const int i = blockIdx.x * SCAN_B + tid;
  unsigned int d = (i < N_NODES) ? (deg[i] - 1u) : 0u;
  buf[tid] = d;
  __syncthreads();
  for (int off = 1; off < SCAN_B; off <<= 1) {
    unsigned int t = (tid >= off) ? buf[tid - off] : 0u;
    __syncthreads();
    buf[tid] += t;
    __syncthreads();
  }
  if (i < N_NODES) rowptr[i] = buf[tid] - d;  // local exclusive
  if (tid == SCAN_B - 1) bsum[blockIdx.x] = buf[tid];
}

__global__ __launch_bounds__(64) void scan2_k(const unsigned int* __restrict__ bsum,
                                              unsigned int* __restrict__ boff,
                                              unsigned int* __restrict__ rowptr) {
  int lane = threadIdx.x;
  unsigned int v = (lane < SCAN_NB) ? bsum[lane] : 0u;
  unsigned int incl = v;
#pragma unroll
  for (int off = 1; off < 64; off <<= 1) {
    unsigned int t = __shfl_up(incl, off, 64);
    if (lane >= off) incl += t;
  }
  if (lane < SCAN_NB) boff[lane] = incl - v;
  if (lane == 63) rowptr[N_NODES] = incl;
}

__global__ __launch_bounds__(SCAN_B) void scan3_k(const unsigned int* __restrict__ boff,
                                                  unsigned int* __restrict__ rowptr) {
  int i = blockIdx.x * SCAN_B + threadIdx.x;
  if (i < N_NODES) rowptr[i] += boff[blockIdx.x];
}

// atomic-free CSR fill using precomputed ranks
__global__ __launch_bounds__(256) void fill_k(const int* __restrict__ rows,
                                              const int* __restrict__ cols,
                                              const unsigned int* __restrict__ rowptr,
                                              const unsigned int* __restrict__ rank,
                                              unsigned int* __restrict__ csr) {
  int e = blockIdx.x * 256 + threadIdx.x;
  if (e >= N_EDGES) return;
  csr[rowptr[cols[e]] + rank[e] - 1u] = (unsigned int)rows[e];
}

// ---------------- aggregation: AGG = A_norm * Z  (gather, unroll-4) ----------
__global__ __launch_bounds__(256) void gather_k(const unsigned int* __restrict__ rowptr,
                                                const unsigned int* __restrict__ csr,
                                                const float* __restrict__ dinv,
                                                const float* __restrict__ Z,
                                                float* __restrict__ AGG) {
  int wid = (blockIdx.x * 256 + threadIdx.x) >> 6;  // node id
  int lane = threadIdx.x & 63;
  if (wid >= N_NODES) return;
  const float2* Z2 = (const float2*)Z;
  float di = dinv[wid];
  float2 z = Z2[(size_t)wid * 64 + lane];
  float sx = di * z.x, sy = di * z.y;
  unsigned int p = rowptr[wid], p1 = rowptr[wid + 1];
  for (; p + 4 <= p1; p += 4) {
    unsigned int s0 = csr[p], s1 = csr[p + 1], s2 = csr[p + 2], s3 = csr[p + 3];
    float w0 = dinv[s0], w1 = dinv[s1], w2 = dinv[s2], w3 = dinv[s3];
    float2 v0 = Z2[(size_t)s0 * 64 + lane];
    float2 v1 = Z2[(size_t)s1 * 64 + lane];
    float2 v2 = Z2[(size_t)s2 * 64 + lane];
    float2 v3 = Z2[(size_t)s3 * 64 + lane];
    sx += w0 * v0.x + w1 * v1.x + w2 * v2.x + w3 * v3.x;
    sy += w0 * v0.y + w1 * v1.y + w2 * v2.y + w3 * v3.y;
  }
  for (; p < p1; ++p) {
    unsigned int s0 = csr[p];
    float w0 = dinv[s0];
    float2 v0 = Z2[(size_t)s0 * 64 + lane];
    sx += w0 * v0.x;
    sy += w0 * v0.y;
  }
  float2 r;
  r.x = sx * di;
  r.y = sy * di;
  ((float2*)AGG)[(size_t)wid * 64 + lane] = r;
}

// ---------------- fused GEMM + bias + PReLU ----------------
// 128x128 tile, 256 threads, 8x8 micro-tile, K chunks of 32.
// sZ row-major [128][33] (pad 1): broadcast reads conflict-free.
__global__ __launch_bounds__(256) void gemm_k(const float* __restrict__ P,
                                              const float* __restrict__ W,
                                              const float* __restrict__ bias,
                                              const float* __restrict__ alpha,
                                              float* __restrict__ out) {
  __shared__ float sW[32 * 128];
  __shared__ float sZ[128 * 33];
  const int tid = threadIdx.x;
  const int rb = blockIdx.x * 128;
  const int rg = tid >> 4, cg = tid & 15;
  const int r0 = rg * 8, c0 = cg * 8;
  float acc[8][8];
#pragma unroll
  for (int i = 0; i < 8; ++i)
#pragma unroll
    for (int j = 0; j < 8; ++j) acc[i][j] = 0.f;

  for (int kc = 0; kc < 128; kc += 32) {
    const float4* Wg = (const float4*)(W + (size_t)kc * 128);
#pragma unroll
    for (int i = 0; i < 4; ++i)
      ((float4*)sW)[tid + i * 256] = Wg[tid + i * 256];
#pragma unroll
    for (int i = 0; i < 4; ++i) {
      int idx = tid + i * 256;  // 0..1023
      int r = idx >> 3, k4 = idx & 7;
      int gr = rb + r;
      float4 v = make_float4(0.f, 0.f, 0.f, 0.f);
      if (gr < N_NODES) v = *(const float4*)(P + (size_t)gr * D + kc + k4 * 4);
      float* dst = &sZ[r * 33 + k4 * 4];
      dst[0] = v.x; dst[1] = v.y; dst[2] = v.z; dst[3] = v.w;
    }
    __syncthreads();
#pragma unroll 8
    for (int k = 0; k < 32; ++k) {
      float zz[8], ww[8];
#pragma unroll
      for (int i = 0; i < 8; ++i) zz[i] = sZ[(r0 + i) * 33 + k];
      float4 wa = *(const float4*)&sW[k * 128 + c0];
      float4 wb = *(const float4*)&sW[k * 128 + c0 + 4];
      ww[0] = wa.x; ww[1] = wa.y; ww[2] = wa.z; ww[3] = wa.w;
      ww[4] = wb.x; ww[5] = wb.y; ww[6] = wb.z; ww[7] = wb.w;
#pragma unroll
      for (int i = 0; i < 8; ++i)
#pragma unroll
        for (int j = 0; j < 8; ++j) acc[i][j] = fmaf(zz[i], ww[j], acc[i][j]);
    }
    __syncthreads();
  }

  float bl[8], al[8];
#pragma unroll
  for (int j = 0; j < 8; ++j) {
    bl[j] = bias[c0 + j];
    al[j] = alpha[c0 + j];
  }
#pragma unroll
  for (int i = 0; i < 8; ++i) {
    int gr = rb + r0 + i;
    if (gr >= N_NODES) continue;
    float o[8];
#pragma unroll
    for (int j = 0; j < 8; ++j) {
      float v = acc[i][j] + bl[j];
      o[j] = v >= 0.f ? v : al[j] * v;
    }
    float4* dst = (float4*)(out + (size_t)gr * D + c0);
    dst[0] = make_float4(o[0], o[1], o[2], o[3]);
    dst[1] = make_float4(o[4], o[5], o[6], o[7]);
  }
}

// ---------------- launch ----------------

extern "C" void kernel_launch(void* const* d_in, const int* in_sizes, int n_in,
                              void* d_out, int out_size, void* d_ws, size_t ws_size,
                              hipStream_t stream) {
  const float* x      = (const float*)d_in[0];
  const int*   ei     = (const int*)d_in[1];   // [2, E] int32
  const float* Ws     = (const float*)d_in[2];
  const float* bs     = (const float*)d_in[3];
  const float* alphas = (const float*)d_in[4];
  float* out = (float*)d_out;

  const int* rows = ei;            // source
  const int* cols = ei + N_EDGES;  // target

  char* ws = (char*)d_ws;
  const size_t NPAD = (((size_t)N_NODES * 4 + 255) / 256) * 256;
  const size_t NP1PAD = ((((size_t)N_NODES + 1) * 4 + 255) / 256) * 256;
  float*        dinv   = (float*)ws;             ws += NPAD;
  unsigned int* rowptr = (unsigned int*)ws;      ws += NP1PAD;
  unsigned int* deg    = (unsigned int*)ws;      ws += NPAD;
  unsigned int* bsum   = (unsigned int*)ws;      ws += 256;  // 49 uints
  unsigned int* boff   = (unsigned int*)ws;      ws += 256;
  unsigned int* csr    = (unsigned int*)ws;      ws += (size_t)N_EDGES * 4;
  float*        AGG    = (float*)ws;
  unsigned int* rank = (unsigned int*)AGG;  // rank (E uints) overlays AGG, dead before gather
  float* Z = out;

  deg_init_k<<<(N_NODES + 255) / 256, 256, 0, stream>>>(deg);
  deg_count_k<<<(N_EDGES + 255) / 256, 256, 0, stream>>>(cols, deg, rank);
  dinv_k<<<(N_NODES + 255) / 256, 256, 0, stream>>>(dinv, deg);
  scan1_k<<<SCAN_NB, SCAN_B, 0, stream>>>(deg, rowptr, bsum);
  scan2_k<<<1, 64, 0, stream>>>(bsum, boff, rowptr);
  scan3_k<<<SCAN_NB, SCAN_B, 0, stream>>>(boff, rowptr);
  fill_k<<<(N_EDGES + 255) / 256, 256, 0, stream>>>(rows, cols, rowptr, rank, csr);

  for (int l = 0; l < L; ++l) {
    const float* zin = (l == 0) ? x : Z;
    gather_k<<<(N_NODES * 64 + 255) / 256, 256, 0, stream>>>(rowptr, csr, dinv, zin, AGG);
    gemm_k<<<(N_NODES + 127) / 128, 256, 0, stream>>>(
        AGG, Ws + (size_t)l * D * D, bs + (size_t)l * D, alphas + (size_t)l * D, Z);
  }
}

// Round 5
// 338.208 us; speedup vs baseline: 12.4704x; 1.0125x over previous
//
#include <hip/hip_runtime.h>

#define N_NODES 50000
#define N_EDGES 800000
#define D 128
#define L 3
#define SCAN_B 1024
#define SCAN_NB ((N_NODES + SCAN_B - 1) / SCAN_B)  // 49

// ---------------- degree / normalization ----------------

__global__ __launch_bounds__(256) void deg_init_k(unsigned int* deg) {
  int i = blockIdx.x * 256 + threadIdx.x;
  if (i < N_NODES) deg[i] = 1u;  // self-loop
}

// count degree AND capture per-edge rank -> atomic-free fill later
__global__ __launch_bounds__(256) void deg_count_k(const int* __restrict__ col,
                                                   unsigned int* deg,
                                                   unsigned int* __restrict__ rank) {
  int e = blockIdx.x * 256 + threadIdx.x;
  if (e < N_EDGES) rank[e] = atomicAdd(&deg[col[e]], 1u);  // >=1 (init 1)
}

__global__ __launch_bounds__(256) void dinv_k(float* dinv_f, const unsigned int* deg) {
  int i = blockIdx.x * 256 + threadIdx.x;
  if (i < N_NODES) dinv_f[i] = rsqrtf((float)deg[i]);
}

// ---------------- CSR build: hierarchical scan ----------------
__global__ __launch_bounds__(SCAN_B) void scan1_k(const unsigned int* __restrict__ deg,
                                                  unsigned int* __restrict__ rowptr,
                                                  unsigned int* __restrict__ bsum) {
  __shared__ unsigned int buf[SCAN_B];
  const int tid = threadIdx.x;
  const int i = blockIdx.x * SCAN_B + tid;
  unsigned int d = (i < N_NODES) ? (deg[i] - 1u) : 0u;
  buf[tid] = d;
  __syncthreads();
  for (int off = 1; off < SCAN_B; off <<= 1) {
    unsigned int t = (tid >= off) ? buf[tid - off] : 0u;
    __syncthreads();
    buf[tid] += t;
    __syncthreads();
  }
  if (i < N_NODES) rowptr[i] = buf[tid] - d;  // local exclusive
  if (tid == SCAN_B - 1) bsum[blockIdx.x] = buf[tid];
}

__global__ __launch_bounds__(64) void scan2_k(const unsigned int* __restrict__ bsum,
                                              unsigned int* __restrict__ boff,
                                              unsigned int* __restrict__ rowptr) {
  int lane = threadIdx.x;
  unsigned int v = (lane < SCAN_NB) ? bsum[lane] : 0u;
  unsigned int incl = v;
#pragma unroll
  for (int off = 1; off < 64; off <<= 1) {
    unsigned int t = __shfl_up(incl, off, 64);
    if (lane >= off) incl += t;
  }
  if (lane < SCAN_NB) boff[lane] = incl - v;
  if (lane == 63) rowptr[N_NODES] = incl;
}

__global__ __launch_bounds__(SCAN_B) void scan3_k(const unsigned int* __restrict__ boff,
                                                  unsigned int* __restrict__ rowptr) {
  int i = blockIdx.x * SCAN_B + threadIdx.x;
  if (i < N_NODES) rowptr[i] += boff[blockIdx.x];
}

// atomic-free CSR fill using precomputed ranks
__global__ __launch_bounds__(256) void fill_k(const int* __restrict__ rows,
                                              const int* __restrict__ cols,
                                              const unsigned int* __restrict__ rowptr,
                                              const unsigned int* __restrict__ rank,
                                              unsigned int* __restrict__ csr) {
  int e = blockIdx.x * 256 + threadIdx.x;
  if (e >= N_EDGES) return;
  csr[rowptr[cols[e]] + rank[e] - 1u] = (unsigned int)rows[e];
}

// ---------------- aggregation: AGG = A_norm * Z ----------------
// one wave per node; per 64-edge chunk: lanes cooperatively load (src, dinv),
// then shfl-broadcast while keeping 8 independent Z-row loads in flight.
__global__ __launch_bounds__(256) void gather_k(const unsigned int* __restrict__ rowptr,
                                                const unsigned int* __restrict__ csr,
                                                const float* __restrict__ dinv,
                                                const float* __restrict__ Z,
                                                float* __restrict__ AGG) {
  int wid = (blockIdx.x * 256 + threadIdx.x) >> 6;  // node id
  int lane = threadIdx.x & 63;
  if (wid >= N_NODES) return;
  const float2* Z2 = (const float2*)Z;
  float di = dinv[wid];
  float2 z = Z2[(size_t)wid * 64 + lane];
  float sx = di * z.x, sy = di * z.y;
  unsigned int p0 = rowptr[wid], p1 = rowptr[wid + 1];
  for (unsigned int base = p0; base < p1; base += 64u) {
    unsigned int cnt = p1 - base;
    if (cnt > 64u) cnt = 64u;
    unsigned int s = 0u;
    float w = 0.f;
    if (lane < (int)cnt) {
      s = csr[base + lane];
      w = dinv[s];
    }
    unsigned int j = 0;
    for (; j + 8u <= cnt; j += 8u) {
      unsigned int ss[8];
      float wws[8];
#pragma unroll
      for (int t = 0; t < 8; ++t) {
        ss[t] = __shfl(s, (int)(j + t), 64);
        wws[t] = __shfl(w, (int)(j + t), 64);
      }
      float2 v[8];
#pragma unroll
      for (int t = 0; t < 8; ++t) v[t] = Z2[(size_t)ss[t] * 64 + lane];
#pragma unroll
      for (int t = 0; t < 8; ++t) {
        sx += wws[t] * v[t].x;
        sy += wws[t] * v[t].y;
      }
    }
    for (; j < cnt; ++j) {
      unsigned int s0 = __shfl(s, (int)j, 64);
      float w0 = __shfl(w, (int)j, 64);
      float2 v0 = Z2[(size_t)s0 * 64 + lane];
      sx += w0 * v0.x;
      sy += w0 * v0.y;
    }
  }
  float2 r;
  r.x = sx * di;
  r.y = sy * di;
  ((float2*)AGG)[(size_t)wid * 64 + lane] = r;
}

// ---------------- fused GEMM + bias + PReLU ----------------
// 128x128 tile, 256 threads, 8x8 micro-tile, K chunks of 32.
// sZT transposed [k][r] with 132 pitch: zz reads are 2x ds_read_b128.
__global__ __launch_bounds__(256) void gemm_k(const float* __restrict__ P,
                                              const float* __restrict__ W,
                                              const float* __restrict__ bias,
                                              const float* __restrict__ alpha,
                                              float* __restrict__ out) {
  __shared__ float sW[32 * 128];
  __shared__ float sZT[32 * 132];
  const int tid = threadIdx.x;
  const int rb = blockIdx.x * 128;
  const int rg = tid >> 4, cg = tid & 15;
  const int r0 = rg * 8, c0 = cg * 8;
  float acc[8][8];
#pragma unroll
  for (int i = 0; i < 8; ++i)
#pragma unroll
    for (int j = 0; j < 8; ++j) acc[i][j] = 0.f;

  for (int kc = 0; kc < 128; kc += 32) {
    const float4* Wg = (const float4*)(W + (size_t)kc * 128);
#pragma unroll
    for (int i = 0; i < 4; ++i)
      ((float4*)sW)[tid + i * 256] = Wg[tid + i * 256];
#pragma unroll
    for (int i = 0; i < 4; ++i) {
      int idx = tid + i * 256;  // 0..1023
      int r = idx >> 3, k4 = idx & 7;
      int gr = rb + r;
      float4 v = make_float4(0.f, 0.f, 0.f, 0.f);
      if (gr < N_NODES) v = *(const float4*)(P + (size_t)gr * D + kc + k4 * 4);
      sZT[(k4 * 4 + 0) * 132 + r] = v.x;
      sZT[(k4 * 4 + 1) * 132 + r] = v.y;
      sZT[(k4 * 4 + 2) * 132 + r] = v.z;
      sZT[(k4 * 4 + 3) * 132 + r] = v.w;
    }
    __syncthreads();
#pragma unroll 8
    for (int k = 0; k < 32; ++k) {
      float4 za = *(const float4*)&sZT[k * 132 + r0];
      float4 zb = *(const float4*)&sZT[k * 132 + r0 + 4];
      float4 wa = *(const float4*)&sW[k * 128 + c0];
      float4 wb = *(const float4*)&sW[k * 128 + c0 + 4];
      float zz[8] = {za.x, za.y, za.z, za.w, zb.x, zb.y, zb.z, zb.w};
      float ww[8] = {wa.x, wa.y, wa.z, wa.w, wb.x, wb.y, wb.z, wb.w};
#pragma unroll
      for (int i = 0; i < 8; ++i)
#pragma unroll
        for (int j = 0; j < 8; ++j) acc[i][j] = fmaf(zz[i], ww[j], acc[i][j]);
    }
    __syncthreads();
  }

  float bl[8], al[8];
#pragma unroll
  for (int j = 0; j < 8; ++j) {
    bl[j] = bias[c0 + j];
    al[j] = alpha[c0 + j];
  }
#pragma unroll
  for (int i = 0; i < 8; ++i) {
    int gr = rb + r0 + i;
    if (gr >= N_NODES) continue;
    float o[8];
#pragma unroll
    for (int j = 0; j < 8; ++j) {
      float v = acc[i][j] + bl[j];
      o[j] = v >= 0.f ? v : al[j] * v;
    }
    float4* dst = (float4*)(out + (size_t)gr * D + c0);
    dst[0] = make_float4(o[0], o[1], o[2], o[3]);
    dst[1] = make_float4(o[4], o[5], o[6], o[7]);
  }
}

// ---------------- launch ----------------

extern "C" void kernel_launch(void* const* d_in, const int* in_sizes, int n_in,
                              void* d_out, int out_size, void* d_ws, size_t ws_size,
                              hipStream_t stream) {
  const float* x      = (const float*)d_in[0];
  const int*   ei     = (const int*)d_in[1];   // [2, E] int32
  const float* Ws     = (const float*)d_in[2];
  const float* bs     = (const float*)d_in[3];
  const float* alphas = (const float*)d_in[4];
  float* out = (float*)d_out;

  const int* rows = ei;            // source
  const int* cols = ei + N_EDGES;  // target

  char* ws = (char*)d_ws;
  const size_t NPAD = (((size_t)N_NODES * 4 + 255) / 256) * 256;
  const size_t NP1PAD = ((((size_t)N_NODES + 1) * 4 + 255) / 256) * 256;
  float*        dinv   = (float*)ws;             ws += NPAD;
  unsigned int* rowptr = (unsigned int*)ws;      ws += NP1PAD;
  unsigned int* deg    = (unsigned int*)ws;      ws += NPAD;
  unsigned int* bsum   = (unsigned int*)ws;      ws += 256;  // 49 uints
  unsigned int* boff   = (unsigned int*)ws;      ws += 256;
  unsigned int* csr    = (unsigned int*)ws;      ws += (size_t)N_EDGES * 4;
  float*        AGG    = (float*)ws;
  unsigned int* rank = (unsigned int*)AGG;  // overlays AGG, dead before gather
  float* Z = out;

  deg_init_k<<<(N_NODES + 255) / 256, 256, 0, stream>>>(deg);
  deg_count_k<<<(N_EDGES + 255) / 256, 256, 0, stream>>>(cols, deg, rank);
  dinv_k<<<(N_NODES + 255) / 256, 256, 0, stream>>>(dinv, deg);
  scan1_k<<<SCAN_NB, SCAN_B, 0, stream>>>(deg, rowptr, bsum);
  scan2_k<<<1, 64, 0, stream>>>(bsum, boff, rowptr);
  scan3_k<<<SCAN_NB, SCAN_B, 0, stream>>>(boff, rowptr);
  fill_k<<<(N_EDGES + 255) / 256, 256, 0, stream>>>(rows, cols, rowptr, rank, csr);

  for (int l = 0; l < L; ++l) {
    const float* zin = (l == 0) ? x : Z;
    gather_k<<<(N_NODES * 64 + 255) / 256, 256, 0, stream>>>(rowptr, csr, dinv, zin, AGG);
    gemm_k<<<(N_NODES + 127) / 128, 256, 0, stream>>>(
        AGG, Ws + (size_t)l * D * D, bs + (size_t)l * D, alphas + (size_t)l * D, Z);
  }
}